// Round 8
// baseline (2408.476 us; speedup 1.0000x reference)
//
#include <hip/hip_runtime.h>

#define DT 5e-5f
#define SPRING_Y 30000.0f
#define DASHPOT 100.0f
// exp(-DT * DRAG_DAMPING) = exp(-5e-5)
#define DRAG 0.9999500012499792f

// xv layout: xv[2*i] = position, xv[2*i+1] = velocity (w unused).
// 32B per vertex, 32B-aligned -> both halves in ONE 64B line.
// adj entry: (neighbor, 1/rest as bits); force formula is symmetric, no sign.
// Two build modes:
//   stride mode (preferred, if ws fits): adj[v*64 + slot], slot from atomicAdd
//     on deg[v] -- no count/scan kernels at all.
//   CSR mode (fallback): exact 2*ns entries via count+scan+fill.

// ---------- common ----------

__global__ void init_k(const float* __restrict__ x0, float4* __restrict__ xv,
                       int* __restrict__ deg, int nv) {
    int i = blockIdx.x * blockDim.x + threadIdx.x;
    if (i < nv) {
        xv[2 * i]     = make_float4(x0[3 * i], x0[3 * i + 1], x0[3 * i + 2], 0.0f);
        xv[2 * i + 1] = make_float4(0.0f, 0.0f, 0.0f, 0.0f);
        deg[i] = 0;
    }
}

// ---------- stride-mode build ----------

__global__ void fill_stride_k(const int2* __restrict__ springs,
                              const float* __restrict__ rest,
                              int* __restrict__ deg, int2* __restrict__ adj,
                              int ns, int S) {
    int s = blockIdx.x * blockDim.x + threadIdx.x;
    if (s < ns) {
        int2 p = springs[s];
        int ir = __float_as_int(1.0f / rest[s]);
        int a = atomicAdd(&deg[p.x], 1);
        adj[p.x * S + a] = make_int2(p.y, ir);
        int b = atomicAdd(&deg[p.y], 1);
        adj[p.y * S + b] = make_int2(p.x, ir);
    }
}

// ---------- CSR-mode build (fallback) ----------

__global__ void count_k(const int2* __restrict__ springs, int* __restrict__ deg, int ns) {
    int s = blockIdx.x * blockDim.x + threadIdx.x;
    if (s < ns) {
        int2 p = springs[s];
        atomicAdd(&deg[p.x], 1);
        atomicAdd(&deg[p.y], 1);
    }
}

__global__ void scan1_k(const int* __restrict__ deg, int* __restrict__ off,
                        int* __restrict__ partials, int nv) {
    __shared__ int sh[256];
    int t = threadIdx.x;
    int g = blockIdx.x * 256 + t;
    int v = (g < nv) ? deg[g] : 0;
    sh[t] = v;
    __syncthreads();
    for (int d = 1; d < 256; d <<= 1) {
        int x = (t >= d) ? sh[t - d] : 0;
        __syncthreads();
        sh[t] += x;
        __syncthreads();
    }
    if (g < nv) off[g] = sh[t] - v;
    if (t == 255) partials[blockIdx.x] = sh[255];
}

__global__ void scan2_k(int* __restrict__ partials, int nb) {
    __shared__ int sh[512];
    int t = threadIdx.x;
    int v = (t < nb) ? partials[t] : 0;
    sh[t] = v;
    __syncthreads();
    for (int d = 1; d < 512; d <<= 1) {
        int x = (t >= d) ? sh[t - d] : 0;
        __syncthreads();
        sh[t] += x;
        __syncthreads();
    }
    if (t < nb) partials[t] = sh[t] - v;
}

__global__ void scan3_k(int* __restrict__ off, int* __restrict__ cursor,
                        const int* __restrict__ partials, int nv) {
    int g = blockIdx.x * 256 + threadIdx.x;
    if (g < nv) {
        int o = off[g] + partials[blockIdx.x];
        off[g] = o;
        cursor[g] = o;
    }
}

__global__ void fill_csr_k(const int2* __restrict__ springs, const float* __restrict__ rest,
                           int* __restrict__ cursor, int2* __restrict__ adj, int ns) {
    int s = blockIdx.x * blockDim.x + threadIdx.x;
    if (s < ns) {
        int2 p = springs[s];
        int ir = __float_as_int(1.0f / rest[s]);
        int a = atomicAdd(&cursor[p.x], 1);
        adj[a] = make_int2(p.y, ir);
        int b = atomicAdd(&cursor[p.y], 1);
        adj[b] = make_int2(p.x, ir);
    }
}

// ---------- fused per-substep kernel: 8 lanes/vertex, software-pipelined
// (adj depth-2, gather depth-1); exec-masked ragged loop, zero wasted gathers ----------

__global__ void __launch_bounds__(256) substep_k(
        const float4* __restrict__ xvin, float4* __restrict__ xvout,
        const int2* __restrict__ adj, const int* __restrict__ off,
        const int* __restrict__ deg, const float* __restrict__ mass,
        int nv, int S, int last) {
    int gid = blockIdx.x * blockDim.x + threadIdx.x;
    int vid = gid >> 3;
    int sub = gid & 7;
    if (vid >= nv) return;

    float4 xa = xvin[2 * vid];
    float4 va = xvin[2 * vid + 1];
    int s0 = S ? (vid * S) : off[vid];
    int s1 = s0 + deg[vid];

    float fx = 0.0f, fy = 0.0f, fz = 0.0f;
    int j = s0 + sub;
    if (j < s1) {
        // pipeline fill
        int2 e0 = adj[j];
        int2 e1 = adj[min(j + 8, last)];
        float4 xb0 = xvin[2 * e0.x];
        float4 vb0 = xvin[2 * e0.x + 1];
        for (;;) {
            int2 e2 = adj[min(j + 16, last)];
            bool more = (j + 8) < s1;
            float4 xb1 = xb0, vb1 = vb0;
            if (more) {                       // exec-masked: no wasted gathers
                xb1 = xvin[2 * e1.x];
                vb1 = xvin[2 * e1.x + 1];
            }

            // compute current entry (gathers for next are in flight)
            float invr = __int_as_float(e0.y);
            float dx = xb0.x - xa.x, dy = xb0.y - xa.y, dz = xb0.z - xa.z;
            float len = sqrtf(dx * dx + dy * dy + dz * dz);
            float il = 1.0f / len;
            float ddx = dx * il, ddy = dy * il, ddz = dz * il;
            float vrel = (vb0.x - va.x) * ddx + (vb0.y - va.y) * ddy + (vb0.z - va.z) * ddz;
            float coef = SPRING_Y * (len * invr - 1.0f) + DASHPOT * vrel;
            fx += coef * ddx;
            fy += coef * ddy;
            fz += coef * ddz;

            if (!more) break;
            j += 8;
            e0 = e1; e1 = e2;
            xb0 = xb1; vb0 = vb1;
        }
    }

    // reduce across the 8 lanes of this vertex (xor stays within the group)
    fx += __shfl_xor(fx, 1);
    fx += __shfl_xor(fx, 2);
    fx += __shfl_xor(fx, 4);
    fy += __shfl_xor(fy, 1);
    fy += __shfl_xor(fy, 2);
    fy += __shfl_xor(fy, 4);
    fz += __shfl_xor(fz, 1);
    fz += __shfl_xor(fz, 2);
    fz += __shfl_xor(fz, 4);

    if (sub == 0) {
        float m = mass[vid];
        fz += m * (-9.8f);
        float invm = 1.0f / m;

        va.x = (va.x + DT * fx * invm) * DRAG;
        va.y = (va.y + DT * fy * invm) * DRAG;
        va.z = (va.z + DT * fz * invm) * DRAG;

        xa.x += DT * va.x;
        xa.y += DT * va.y;
        xa.z += DT * va.z;
        xa.z = fmaxf(xa.z, 0.0f);
        if (xa.z == 0.0f) va.z = 0.0f;

        xvout[2 * vid]     = xa;
        xvout[2 * vid + 1] = va;
    }
}

__global__ void pack_k(const float4* __restrict__ xv, float* __restrict__ out, int nv) {
    int i = blockIdx.x * blockDim.x + threadIdx.x;
    if (i < nv) {
        float4 x = xv[2 * i];
        out[3 * i + 0] = x.x;
        out[3 * i + 1] = x.y;
        out[3 * i + 2] = x.z;
    }
}

extern "C" void kernel_launch(void* const* d_in, const int* in_sizes, int n_in,
                              void* d_out, int out_size, void* d_ws, size_t ws_size,
                              hipStream_t stream) {
    const float* x0      = (const float*)d_in[0];   // (NV,3) fp32
    const int2*  springs = (const int2*)d_in[1];    // (NS,2) int32
    const float* rest    = (const float*)d_in[2];   // (NS,)  fp32
    const float* mass    = (const float*)d_in[3];   // (NV,)  fp32

    const int ns = in_sizes[2];        // 1,000,000
    const int nv = in_sizes[3];        // 100,000
    const int nb = (nv + 255) / 256;

    // fixed workspace regions
    char* ws = (char*)d_ws;
    size_t o = 0;
    float4* xva = (float4*)(ws + o); o += (size_t)nv * 32;   // x,v interleaved
    float4* xvb = (float4*)(ws + o); o += (size_t)nv * 32;
    int* deg      = (int*)(ws + o);  o += (((size_t)nv * 4 + 15) & ~15ull);
    int* off      = (int*)(ws + o);  o += ((((size_t)nv + 1) * 4 + 15) & ~15ull);
    int* cursor   = (int*)(ws + o);  o += (((size_t)nv * 4 + 15) & ~15ull);
    int* partials = (int*)(ws + o);  o += (((size_t)nb * 4 + 15) & ~15ull);
    int2* adj     = (int2*)(ws + o);
    size_t adj_cap = (ws_size > o) ? (ws_size - o) : 0;

    const int STRIDE = 64;             // max degree bound; Poisson(20) tail ~ e^-30
    bool stride_mode = adj_cap >= (size_t)nv * STRIDE * 8;

    dim3 blk(256);
    dim3 vgrid(nb);
    dim3 sgrid((ns + 255) / 256);
    dim3 subgrid(((size_t)nv * 8 + 255) / 256);   // 8 lanes per vertex

    init_k<<<vgrid, blk, 0, stream>>>(x0, xva, deg, nv);

    int S, last;
    if (stride_mode) {
        fill_stride_k<<<sgrid, blk, 0, stream>>>(springs, rest, deg, adj, ns, STRIDE);
        S = STRIDE;
        last = nv * STRIDE - 1;
    } else {
        count_k<<<sgrid, blk, 0, stream>>>(springs, deg, ns);
        scan1_k<<<vgrid, blk, 0, stream>>>(deg, off, partials, nv);
        scan2_k<<<1, 512, 0, stream>>>(partials, nb);
        scan3_k<<<vgrid, blk, 0, stream>>>(off, cursor, partials, nv);
        fill_csr_k<<<sgrid, blk, 0, stream>>>(springs, rest, cursor, adj, ns);
        S = 0;
        last = 2 * ns - 1;
    }

    const int NSUB = 100;
    float4* xi = xva;
    float4* xo = xvb;
    for (int t = 0; t < NSUB; ++t) {
        substep_k<<<subgrid, blk, 0, stream>>>(xi, xo, adj, off, deg, mass, nv, S, last);
        float4* tmp = xi; xi = xo; xo = tmp;
    }
    pack_k<<<vgrid, blk, 0, stream>>>(xi, (float*)d_out, nv);
}

// Round 9
// 2210.870 us; speedup vs baseline: 1.0894x; 1.0894x over previous
//
#include <hip/hip_runtime.h>

#define DT 5e-5f
#define SPRING_Y 30000.0f
#define DASHPOT 100.0f
// exp(-DT * DRAG_DAMPING) = exp(-5e-5)
#define DRAG 0.9999500012499792f

// xv layout: xv[2*i] = position, xv[2*i+1] = velocity (w unused).
// 32B per vertex, 32B-aligned -> both halves in ONE 64B line.
// adj entry: (neighbor, 1/rest as bits); force formula is symmetric, no sign.
// Stride layout: vertex v's entries at adj[v*64 .. v*64+deg[v]), slots filled
// by atomicAdd on deg during fill -- no count/scan kernels needed.
// STRIDE=64 >= max degree w.h.p. (Poisson(20) tail ~ e^-30).

// ---------- one-time (per launch) build ----------

__global__ void init_k(const float* __restrict__ x0, float4* __restrict__ xv,
                       int* __restrict__ deg, int nv) {
    int i = blockIdx.x * blockDim.x + threadIdx.x;
    if (i < nv) {
        xv[2 * i]     = make_float4(x0[3 * i], x0[3 * i + 1], x0[3 * i + 2], 0.0f);
        xv[2 * i + 1] = make_float4(0.0f, 0.0f, 0.0f, 0.0f);
        deg[i] = 0;
    }
}

__global__ void fill_stride_k(const int2* __restrict__ springs,
                              const float* __restrict__ rest,
                              int* __restrict__ deg, int2* __restrict__ adj,
                              int ns, int S) {
    int s = blockIdx.x * blockDim.x + threadIdx.x;
    if (s < ns) {
        int2 p = springs[s];
        int ir = __float_as_int(1.0f / rest[s]);
        int a = atomicAdd(&deg[p.x], 1);
        adj[p.x * S + a] = make_int2(p.y, ir);
        int b = atomicAdd(&deg[p.y], 1);
        adj[p.y * S + b] = make_int2(p.x, ir);
    }
}

// ---------- fused per-substep kernel: 8 lanes/vertex, 1 entry/lane/iter,
// exec-masked ragged loop (no wasted gathers), adj prefetch-1 (clamped) ----------

__global__ void __launch_bounds__(256) substep_k(
        const float4* __restrict__ xvin, float4* __restrict__ xvout,
        const int2* __restrict__ adj, const int* __restrict__ deg,
        const float* __restrict__ mass, int nv, int S, int last) {
    int gid = blockIdx.x * blockDim.x + threadIdx.x;
    int vid = gid >> 3;
    int sub = gid & 7;
    if (vid >= nv) return;

    float4 xa = xvin[2 * vid];
    float4 va = xvin[2 * vid + 1];
    int s0 = vid * S;
    int s1 = s0 + deg[vid];

    float fx = 0.0f, fy = 0.0f, fz = 0.0f;
    int j = s0 + sub;
    if (j < s1) {
        int2 e = adj[j];
        for (;;) {
            int jn = j + 8;
            int2 en = adj[min(jn, last)];   // prefetch next entry (clamped, safe)

            int nb = e.x;
            float4 xb = xvin[2 * nb];
            float4 vb = xvin[2 * nb + 1];
            float invr = __int_as_float(e.y);

            float dx = xb.x - xa.x, dy = xb.y - xa.y, dz = xb.z - xa.z;
            float len = sqrtf(dx * dx + dy * dy + dz * dz);
            float il = 1.0f / len;
            float ddx = dx * il, ddy = dy * il, ddz = dz * il;

            float vrel = (vb.x - va.x) * ddx + (vb.y - va.y) * ddy + (vb.z - va.z) * ddz;
            float coef = SPRING_Y * (len * invr - 1.0f) + DASHPOT * vrel;

            fx += coef * ddx;
            fy += coef * ddy;
            fz += coef * ddz;

            if (jn >= s1) break;
            j = jn;
            e = en;
        }
    }

    // reduce across the 8 lanes of this vertex (xor stays within the group)
    fx += __shfl_xor(fx, 1);
    fx += __shfl_xor(fx, 2);
    fx += __shfl_xor(fx, 4);
    fy += __shfl_xor(fy, 1);
    fy += __shfl_xor(fy, 2);
    fy += __shfl_xor(fy, 4);
    fz += __shfl_xor(fz, 1);
    fz += __shfl_xor(fz, 2);
    fz += __shfl_xor(fz, 4);

    if (sub == 0) {
        float m = mass[vid];
        fz += m * (-9.8f);
        float invm = 1.0f / m;

        va.x = (va.x + DT * fx * invm) * DRAG;
        va.y = (va.y + DT * fy * invm) * DRAG;
        va.z = (va.z + DT * fz * invm) * DRAG;

        xa.x += DT * va.x;
        xa.y += DT * va.y;
        xa.z += DT * va.z;
        xa.z = fmaxf(xa.z, 0.0f);
        if (xa.z == 0.0f) va.z = 0.0f;

        xvout[2 * vid]     = xa;
        xvout[2 * vid + 1] = va;
    }
}

__global__ void pack_k(const float4* __restrict__ xv, float* __restrict__ out, int nv) {
    int i = blockIdx.x * blockDim.x + threadIdx.x;
    if (i < nv) {
        float4 x = xv[2 * i];
        out[3 * i + 0] = x.x;
        out[3 * i + 1] = x.y;
        out[3 * i + 2] = x.z;
    }
}

extern "C" void kernel_launch(void* const* d_in, const int* in_sizes, int n_in,
                              void* d_out, int out_size, void* d_ws, size_t ws_size,
                              hipStream_t stream) {
    const float* x0      = (const float*)d_in[0];   // (NV,3) fp32
    const int2*  springs = (const int2*)d_in[1];    // (NS,2) int32
    const float* rest    = (const float*)d_in[2];   // (NS,)  fp32
    const float* mass    = (const float*)d_in[3];   // (NV,)  fp32

    const int ns = in_sizes[2];        // 1,000,000
    const int nv = in_sizes[3];        // 100,000
    const int nb = (nv + 255) / 256;

    // workspace layout
    char* ws = (char*)d_ws;
    size_t o = 0;
    float4* xva = (float4*)(ws + o); o += (size_t)nv * 32;   // x,v interleaved
    float4* xvb = (float4*)(ws + o); o += (size_t)nv * 32;
    int* deg    = (int*)(ws + o);    o += (((size_t)nv * 4 + 15) & ~15ull);
    int2* adj   = (int2*)(ws + o);                            // nv*64 entries (51.2 MB)

    const int STRIDE = 64;
    const int last = nv * STRIDE - 1;

    dim3 blk(256);
    dim3 vgrid(nb);
    dim3 sgrid((ns + 255) / 256);
    dim3 subgrid(((size_t)nv * 8 + 255) / 256);   // 8 lanes per vertex

    // one-time build (replayed every call; amortized over 100 substeps)
    init_k<<<vgrid, blk, 0, stream>>>(x0, xva, deg, nv);
    fill_stride_k<<<sgrid, blk, 0, stream>>>(springs, rest, deg, adj, ns, STRIDE);

    const int NSUB = 100;
    float4* xi = xva;
    float4* xo = xvb;
    for (int t = 0; t < NSUB; ++t) {
        substep_k<<<subgrid, blk, 0, stream>>>(xi, xo, adj, deg, mass, nv, STRIDE, last);
        float4* tmp = xi; xi = xo; xo = tmp;
    }
    pack_k<<<vgrid, blk, 0, stream>>>(xi, (float*)d_out, nv);
}